// Round 1
// baseline (799.057 us; speedup 1.0000x reference)
//
#include <hip/hip_runtime.h>
#include <math.h>

#define NEG_BIG (-1e30f)

// ---------------------------------------------------------------------------
// Kernel 0: per-LR-pixel parameter transforms + guide downsample.
// P layout [9][256]: 0=cos(th) 1=sin(th) 2=1/(2sx^2+eps) 3=1/(2sy^2+eps)
//                    4=1/(2sr^2+eps) 5..7=guide_lr rgb 8=max(sx,sy)
// ---------------------------------------------------------------------------
__global__ __launch_bounds__(256) void setup_params(
    const float* __restrict__ sx_raw, const float* __restrict__ sy_raw,
    const float* __restrict__ th_raw, const float* __restrict__ sr_raw,
    const float* __restrict__ guide, float* __restrict__ P)
{
    int t = threadIdx.x;
    float sx = expf(sx_raw[t]);
    float sy = expf(sy_raw[t]);
    float th = 3.14159265358979323846f * tanhf(th_raw[t]);
    float sr = expf(sr_raw[t]);
    float sxg = fmaxf(sx, 1e-6f), syg = fmaxf(sy, 1e-6f), srg = fmaxf(sr, 1e-6f);
    P[0*256 + t] = cosf(th);
    P[1*256 + t] = sinf(th);
    P[2*256 + t] = 1.f / (2.f*sxg*sxg + 1e-8f);
    P[3*256 + t] = 1.f / (2.f*syg*syg + 1e-8f);
    P[4*256 + t] = 1.f / (2.f*srg*srg + 1e-8f);
    int i = t >> 4, j = t & 15;
    // bilinear 256->16: ys = 16*i+7.5 -> exact 0.25-weighted 2x2 average
    int y0 = 16*i + 7, x0 = 16*j + 7;
#pragma unroll
    for (int c = 0; c < 3; ++c) {
        const float* g = guide + c*65536;
        P[(5+c)*256 + t] = 0.25f*(g[y0*256 + x0]     + g[y0*256 + x0 + 1] +
                                  g[(y0+1)*256 + x0] + g[(y0+1)*256 + x0 + 1]);
    }
    P[8*256 + t] = fmaxf(sx, sy);
}

// ---------------------------------------------------------------------------
// Kernel 1: transpose feat [384][256] -> feat_t [256][384] (p-major rows)
// 64x64 LDS tiles, fully coalesced both directions, conflict-free (stride 65).
// Grid: 6 c-tiles x 4 p-tiles = 24 blocks x 256 threads.
// ---------------------------------------------------------------------------
__global__ __launch_bounds__(256) void transpose_feat(
    const float* __restrict__ feat, float* __restrict__ feat_t)
{
    __shared__ float tile[64][65];
    int t = threadIdx.x;
    int c0 = (blockIdx.x % 6) * 64;
    int p0 = (blockIdx.x / 6) * 64;
    int lr = t >> 6;    // 0..3
    int lc = t & 63;    // 0..63
#pragma unroll
    for (int rr = 0; rr < 16; ++rr) {
        int c_l = rr*4 + lr;
        tile[c_l][lc] = feat[(c0 + c_l)*256 + p0 + lc];
    }
    __syncthreads();
#pragma unroll
    for (int rr = 0; rr < 16; ++rr) {
        int p_l = rr*4 + lr;
        feat_t[(p0 + p_l)*384 + c0 + lc] = tile[lc][p_l];
    }
}

// ---------------------------------------------------------------------------
// Kernel 2: main fused JBU.
// Block = 1x32 HR pixel strip (Y = blockIdx.y, X = blockIdx.x*32 + q).
// 256 threads = 32 pixels (q) x 8 groups (grp).
// Phase 1: per distinct LR pixel p: multiplicity count (clip-interval x disk)
//          folded as lw' = lw + ln(count); store to LDS W[p][q]; track max.
// Phase 2: s = exp(lw' - m'); den = sum.  (num/den invariant vs reference)
// Phase 3: out[c,pix] = (1/den) * sum_p feat_t[p][c] * W[p][q], 8-ch blocking.
// LDS: 9.25KB params + 32KB W + 1KB red = 42.2KB -> 3 blocks/CU.
// ---------------------------------------------------------------------------
__global__ __launch_bounds__(256, 3) void jbu_main(
    const float* __restrict__ guide, const float* __restrict__ feat_t,
    const float* __restrict__ P, float* __restrict__ out)
{
    __shared__ float sP[9][256];
    __shared__ float W[256][32];
    __shared__ float red[8][32];

    const int t = threadIdx.x;
#pragma unroll
    for (int g = 0; g < 9; ++g) sP[g][t] = P[g*256 + t];
    __syncthreads();

    const int q   = t & 31;
    const int grp = t >> 5;
    const int Y = blockIdx.y;
    const int X = (blockIdx.x << 5) + q;
    const float Yf = (float)Y, Xf = (float)X;

    // R_map: bilinear upsample of max(sx,sy); ys/xs = max(u,0), floor, clamp
    float u = (Yf + 0.5f)*0.0625f - 0.5f;
    float v = (Xf + 0.5f)*0.0625f - 0.5f;
    float ysc = fmaxf(u, 0.f), xsc = fmaxf(v, 0.f);
    int y0 = (int)ysc, x0 = (int)xsc;        // values >= 0, cast == floor
    int y1 = min(y0 + 1, 15), x1 = min(x0 + 1, 15);
    float wy = ysc - (float)y0, wx = xsc - (float)x0;
    float s00 = sP[8][y0*16 + x0], s01 = sP[8][y0*16 + x1];
    float s10 = sP[8][y1*16 + x0], s11 = sP[8][y1*16 + x1];
    float sig = (1.f - wy)*((1.f - wx)*s00 + wx*s01)
              +        wy *((1.f - wx)*s10 + wx*s11);
    float Rf = fminf(fmaxf(ceilf(2.f*sig), 1.f), 8.f);
    int Ri = (int)Rf;
    int R2i = Ri*Ri;

    const int uc = Y >> 4, vc = X >> 4;   // == clip(round(u),0,15) exactly
    const float g0 = guide[          (Y << 8) + X];
    const float g1 = guide[ 65536 + ((Y << 8) + X)];
    const float g2 = guide[131072 + ((Y << 8) + X)];

    // ---- Phase 1: log-weights (+ln count) over distinct LR pixels ----
    float mloc = NEG_BIG;
    const int pbase = grp << 5;
    for (int pi = 0; pi < 32; ++pi) {
        int p = pbase + pi;
        int Pu = p >> 4, Pv = p & 15;
        // dY interval mapping to row Pu under clip(uc+dY,0,15), within [-8,8]
        int ylo = (Pu == 0)  ? -8 : (Pu - uc);
        int yhi = (Pu == 15) ?  8 : (Pu - uc);
        ylo = max(ylo, -8); yhi = min(yhi, 8);
        int xlo = (Pv == 0)  ? -8 : (Pv - vc);
        int xhi = (Pv == 15) ?  8 : (Pv - vc);
        xlo = max(xlo, -8); xhi = min(xhi, 8);
        int cnt = 0;
        if (ylo <= yhi && xlo <= xhi) {
            for (int dY = ylo; dY <= yhi; ++dY) {
                int lim = R2i - dY*dY;
                if (lim >= 0) {
                    int r = (int)sqrtf((float)lim);   // exact for ints <= 64
                    int lo = max(xlo, -r), hi = min(xhi, r);
                    cnt += max(0, hi - lo + 1);
                }
            }
        }
        float lw = NEG_BIG;
        if (cnt > 0) {
            float ctp = sP[0][p], stp = sP[1][p];
            float iAp = sP[2][p], iBp = sP[3][p], iCp = sP[4][p];
            float dxv = Xf - (16.f*(float)Pv + 7.5f);
            float dyv = Yf - (16.f*(float)Pu + 7.5f);
            float a = dxv*ctp + dyv*stp;
            float b = dyv*ctp - dxv*stp;
            float d0 = g0 - sP[5][p], d1 = g1 - sP[6][p], d2 = g2 - sP[7][p];
            float gd = d0*d0 + d1*d1 + d2*d2;
            lw = -(a*a*iAp + b*b*iBp + gd*iCp) + __logf((float)cnt);
            mloc = fmaxf(mloc, lw);
        }
        W[p][q] = lw;
    }
    red[grp][q] = mloc;
    __syncthreads();
    float m = red[0][q];
#pragma unroll
    for (int g = 1; g < 8; ++g) m = fmaxf(m, red[g][q]);
    __syncthreads();   // before red is reused for den

    // ---- Phase 2: exponentiate in place, accumulate denominator ----
    float dloc = 0.f;
    for (int pi = 0; pi < 32; ++pi) {
        int p = pbase + pi;
        float s = __expf(W[p][q] - m);   // NEG_BIG entries underflow to 0
        W[p][q] = s;
        dloc += s;
    }
    red[grp][q] = dloc;
    __syncthreads();   // also publishes all W writes for phase 3
    float den = 0.f;
#pragma unroll
    for (int g = 0; g < 8; ++g) den += red[g][q];
    float inv_den = 1.f / fmaxf(den, 1e-8f);

    // ---- Phase 3: out[c,pix] = inv_den * sum_p feat_t[p][c] * W[p][q] ----
    const int c0 = grp * 48;
    const int outpix = (Y << 8) + X;
    for (int cb = 0; cb < 6; ++cb) {
        int cc = c0 + (cb << 3);
        float a0 = 0.f, a1 = 0.f, a2 = 0.f, a3 = 0.f;
        float a4 = 0.f, a5 = 0.f, a6 = 0.f, a7 = 0.f;
        const float* fbase = feat_t + cc;
#pragma unroll 4
        for (int p = 0; p < 256; ++p) {
            float w = W[p][q];
            const float4* f4 = (const float4*)(fbase + p*384);
            float4 fa = f4[0];
            float4 fb = f4[1];
            a0 += fa.x*w; a1 += fa.y*w; a2 += fa.z*w; a3 += fa.w*w;
            a4 += fb.x*w; a5 += fb.y*w; a6 += fb.z*w; a7 += fb.w*w;
        }
        float* o = out + cc*65536 + outpix;
        o[0*65536] = a0*inv_den; o[1*65536] = a1*inv_den;
        o[2*65536] = a2*inv_den; o[3*65536] = a3*inv_den;
        o[4*65536] = a4*inv_den; o[5*65536] = a5*inv_den;
        o[6*65536] = a6*inv_den; o[7*65536] = a7*inv_den;
    }
}

// ---------------------------------------------------------------------------
extern "C" void kernel_launch(void* const* d_in, const int* in_sizes, int n_in,
                              void* d_out, int out_size, void* d_ws, size_t ws_size,
                              hipStream_t stream)
{
    const float* feat   = (const float*)d_in[0];   // [1,384,16,16]
    const float* guide  = (const float*)d_in[1];   // [1,3,256,256]
    const float* sx_raw = (const float*)d_in[2];   // [1,1,16,16]
    const float* sy_raw = (const float*)d_in[3];
    const float* th_raw = (const float*)d_in[4];
    const float* sr_raw = (const float*)d_in[5];
    float* out = (float*)d_out;                    // [1,384,256,256]

    float* feat_t = (float*)d_ws;                           // 384 KB
    float* P      = (float*)((char*)d_ws + 384*1024);       // 9 KB

    setup_params<<<1, 256, 0, stream>>>(sx_raw, sy_raw, th_raw, sr_raw, guide, P);
    transpose_feat<<<24, 256, 0, stream>>>(feat, feat_t);
    jbu_main<<<dim3(8, 256), 256, 0, stream>>>(guide, feat_t, P, out);
}

// Round 2
// 189.161 us; speedup vs baseline: 4.2242x; 4.2242x over previous
//
#include <hip/hip_runtime.h>
#include <math.h>

#define NEG_BIG (-1e30f)

typedef _Float16 half8 __attribute__((ext_vector_type(8)));
typedef float floatx4 __attribute__((ext_vector_type(4)));

// ---------------------------------------------------------------------------
// Kernel 0: per-LR-pixel parameter transforms + guide downsample.
// P layout [9][256]: 0=cos(th) 1=sin(th) 2=1/(2sx^2+eps) 3=1/(2sy^2+eps)
//                    4=1/(2sr^2+eps) 5..7=guide_lr rgb 8=max(sx,sy)
// ---------------------------------------------------------------------------
__global__ __launch_bounds__(256) void setup_params(
    const float* __restrict__ sx_raw, const float* __restrict__ sy_raw,
    const float* __restrict__ th_raw, const float* __restrict__ sr_raw,
    const float* __restrict__ guide, float* __restrict__ P)
{
    int t = threadIdx.x;
    float sx = expf(sx_raw[t]);
    float sy = expf(sy_raw[t]);
    float th = 3.14159265358979323846f * tanhf(th_raw[t]);
    float sr = expf(sr_raw[t]);
    float sxg = fmaxf(sx, 1e-6f), syg = fmaxf(sy, 1e-6f), srg = fmaxf(sr, 1e-6f);
    P[0*256 + t] = cosf(th);
    P[1*256 + t] = sinf(th);
    P[2*256 + t] = 1.f / (2.f*sxg*sxg + 1e-8f);
    P[3*256 + t] = 1.f / (2.f*syg*syg + 1e-8f);
    P[4*256 + t] = 1.f / (2.f*srg*srg + 1e-8f);
    int i = t >> 4, j = t & 15;
    // bilinear 256->16: ys = 16*i+7.5 -> exact 0.25-weighted 2x2 average
    int y0 = 16*i + 7, x0 = 16*j + 7;
#pragma unroll
    for (int c = 0; c < 3; ++c) {
        const float* g = guide + c*65536;
        P[(5+c)*256 + t] = 0.25f*(g[y0*256 + x0]     + g[y0*256 + x0 + 1] +
                                  g[(y0+1)*256 + x0] + g[(y0+1)*256 + x0 + 1]);
    }
    P[8*256 + t] = fmaxf(sx, sy);
}

// ---------------------------------------------------------------------------
// Kernel 1: feat fp32 [384][256] -> fp16, same (c-major) layout.
// This is exactly the MFMA A-operand layout: A[m=c][k=p].
// ---------------------------------------------------------------------------
__global__ __launch_bounds__(256) void convert_feat(
    const float* __restrict__ feat, _Float16* __restrict__ feat16)
{
    int i = blockIdx.x * 256 + threadIdx.x;   // grid = 384 blocks -> 98304
    feat16[i] = (_Float16)feat[i];
}

// ---------------------------------------------------------------------------
// Kernel 2: main fused JBU.
// Block = 1x32 HR pixel strip (Y = blockIdx.y, X = blockIdx.x*32 + q).
// 256 threads = 32 pixels (q) x 8 p-groups (grp) for the weight phases,
// re-viewed as 4 waves x 96 channels for the MFMA phase.
//
// Phase 1: per distinct LR pixel p: multiplicity count (clip-interval x disk)
//          folded as lw = log_w + ln(count); kept in 32 registers.
// Phase 2: s = exp(lw - m); round to fp16; store to LDS Wb[pix][p] with
//          XOR-swizzled 16B chunks (conflict-free b128 B-frag reads);
//          den = sum of fp16-rounded s (keeps num/den consistent).
// Phase 3: out[c, pix] = invden * (feat16[384,256] @ Wb[256,32])
//          via mfma_f32_16x16x32_f16; A from global (L2-hot), B from LDS.
// LDS ~26.8KB; target 4 blocks/CU.
// ---------------------------------------------------------------------------
__global__ __launch_bounds__(256, 4) void jbu_main(
    const float* __restrict__ guide, const _Float16* __restrict__ feat16,
    const float* __restrict__ P, float* __restrict__ out)
{
    __shared__ float sP[9][256];
    __shared__ __align__(16) _Float16 Wb[32][256];  // row = pixel, swizzled
    __shared__ float red[8][32];
    __shared__ float invden[32];

    const int t = threadIdx.x;
#pragma unroll
    for (int g = 0; g < 9; ++g) sP[g][t] = P[g*256 + t];
    __syncthreads();

    const int q   = t & 31;
    const int grp = t >> 5;
    const int Y = blockIdx.y;
    const int X = (blockIdx.x << 5) + q;
    const float Yf = (float)Y, Xf = (float)X;

    // R_map: bilinear upsample of max(sx,sy)
    float u = (Yf + 0.5f)*0.0625f - 0.5f;
    float v = (Xf + 0.5f)*0.0625f - 0.5f;
    float ysc = fmaxf(u, 0.f), xsc = fmaxf(v, 0.f);
    int y0 = (int)ysc, x0 = (int)xsc;
    int y1 = min(y0 + 1, 15), x1 = min(x0 + 1, 15);
    float wy = ysc - (float)y0, wx = xsc - (float)x0;
    float s00 = sP[8][y0*16 + x0], s01 = sP[8][y0*16 + x1];
    float s10 = sP[8][y1*16 + x0], s11 = sP[8][y1*16 + x1];
    float sig = (1.f - wy)*((1.f - wx)*s00 + wx*s01)
              +        wy *((1.f - wx)*s10 + wx*s11);
    float Rf = fminf(fmaxf(ceilf(2.f*sig), 1.f), 8.f);
    int Ri = (int)Rf;
    int R2i = Ri*Ri;

    const int uc = Y >> 4, vc = X >> 4;   // == clip(round(u),0,15) exactly
    const float g0 = guide[          (Y << 8) + X];
    const float g1 = guide[ 65536 + ((Y << 8) + X)];
    const float g2 = guide[131072 + ((Y << 8) + X)];

    // ---- Phase 1: log-weights (+ln count) over distinct LR pixels ----
    float lw[32];
    float mloc = NEG_BIG;
    const int pbase = grp << 5;
#pragma unroll
    for (int pi = 0; pi < 32; ++pi) {
        int p = pbase + pi;
        int Pu = p >> 4, Pv = p & 15;
        int ylo = (Pu == 0)  ? -8 : (Pu - uc);
        int yhi = (Pu == 15) ?  8 : (Pu - uc);
        ylo = max(ylo, -8); yhi = min(yhi, 8);
        int xlo = (Pv == 0)  ? -8 : (Pv - vc);
        int xhi = (Pv == 15) ?  8 : (Pv - vc);
        xlo = max(xlo, -8); xhi = min(xhi, 8);
        int cnt = 0;
        if (ylo <= yhi && xlo <= xhi) {
            for (int dY = ylo; dY <= yhi; ++dY) {
                int lim = R2i - dY*dY;
                if (lim >= 0) {
                    int r = (int)sqrtf((float)lim);   // exact for ints <= 64
                    int lo = max(xlo, -r), hi = min(xhi, r);
                    cnt += max(0, hi - lo + 1);
                }
            }
        }
        float w = NEG_BIG;
        if (cnt > 0) {
            float ctp = sP[0][p], stp = sP[1][p];
            float iAp = sP[2][p], iBp = sP[3][p], iCp = sP[4][p];
            float dxv = Xf - (16.f*(float)Pv + 7.5f);
            float dyv = Yf - (16.f*(float)Pu + 7.5f);
            float a = dxv*ctp + dyv*stp;
            float b = dyv*ctp - dxv*stp;
            float d0 = g0 - sP[5][p], d1 = g1 - sP[6][p], d2 = g2 - sP[7][p];
            float gd = d0*d0 + d1*d1 + d2*d2;
            w = -(a*a*iAp + b*b*iBp + gd*iCp) + __logf((float)cnt);
            mloc = fmaxf(mloc, w);
        }
        lw[pi] = w;
    }
    red[grp][q] = mloc;
    __syncthreads();
    float m = red[0][q];
#pragma unroll
    for (int g = 1; g < 8; ++g) m = fmaxf(m, red[g][q]);
    __syncthreads();   // before red is reused for den

    // ---- Phase 2: exp, fp16 round, swizzled LDS store, denominator ----
    float dloc = 0.f;
#pragma unroll
    for (int pi = 0; pi < 32; ++pi) {
        int p = pbase + pi;
        float s = __expf(lw[pi] - m);      // NEG_BIG entries underflow to 0
        _Float16 h = (_Float16)s;
        int chunk = ((p >> 3) ^ q) & 31;   // 16B-chunk XOR swizzle
        Wb[q][chunk*8 + (p & 7)] = h;
        dloc += (float)h;                  // den consistent with fp16 weights
    }
    red[grp][q] = dloc;
    __syncthreads();                       // publishes Wb + den partials
    float den = 0.f;
#pragma unroll
    for (int g = 0; g < 8; ++g) den += red[g][q];
    if (grp == 0) invden[q] = 1.f / fmaxf(den, 1e-8f);
    __syncthreads();

    // ---- Phase 3: MFMA GEMM: out[c,pix] = invden * feat16 @ Wb ----
    const int lane = t & 63;
    const int wv   = t >> 6;          // wave 0..3 -> channels wv*96..+96
    const int mrow = lane & 15;
    const int quad = lane >> 4;
    const int c0   = wv * 96;

    floatx4 acc[6][2] = {};
    const _Float16* fbase = feat16 + (c0 + mrow)*256 + quad*8;

#pragma unroll
    for (int ks = 0; ks < 8; ++ks) {
        half8 a[6];
#pragma unroll
        for (int mt = 0; mt < 6; ++mt)
            a[mt] = *(const half8*)(fbase + mt*16*256 + ks*32);
        half8 b[2];
#pragma unroll
        for (int nt = 0; nt < 2; ++nt) {
            int pix = nt*16 + mrow;
            int chunk = ((ks*4 + quad) ^ pix) & 31;
            b[nt] = *(const half8*)(&Wb[pix][chunk*8]);
        }
#pragma unroll
        for (int mt = 0; mt < 6; ++mt)
#pragma unroll
            for (int nt = 0; nt < 2; ++nt)
                acc[mt][nt] = __builtin_amdgcn_mfma_f32_16x16x32_f16(
                    a[mt], b[nt], acc[mt][nt], 0, 0, 0);
    }

    // ---- Epilogue: scale by invden, store (64B segments per 16 lanes) ----
    const int outbase = (Y << 8) + (blockIdx.x << 5);
#pragma unroll
    for (int nt = 0; nt < 2; ++nt) {
        float idv = invden[nt*16 + mrow];
#pragma unroll
        for (int mt = 0; mt < 6; ++mt) {
            int crow = c0 + mt*16 + quad*4;
            float* o = out + (size_t)crow*65536 + outbase + nt*16 + mrow;
#pragma unroll
            for (int r = 0; r < 4; ++r)
                o[(size_t)r*65536] = acc[mt][nt][r] * idv;
        }
    }
}

// ---------------------------------------------------------------------------
extern "C" void kernel_launch(void* const* d_in, const int* in_sizes, int n_in,
                              void* d_out, int out_size, void* d_ws, size_t ws_size,
                              hipStream_t stream)
{
    const float* feat   = (const float*)d_in[0];   // [1,384,16,16]
    const float* guide  = (const float*)d_in[1];   // [1,3,256,256]
    const float* sx_raw = (const float*)d_in[2];   // [1,1,16,16]
    const float* sy_raw = (const float*)d_in[3];
    const float* th_raw = (const float*)d_in[4];
    const float* sr_raw = (const float*)d_in[5];
    float* out = (float*)d_out;                    // [1,384,256,256]

    _Float16* feat16 = (_Float16*)d_ws;                       // 192 KB
    float*    P      = (float*)((char*)d_ws + 256*1024);      // 9 KB

    setup_params<<<1, 256, 0, stream>>>(sx_raw, sy_raw, th_raw, sr_raw, guide, P);
    convert_feat<<<384, 256, 0, stream>>>(feat, feat16);
    jbu_main<<<dim3(8, 256), 256, 0, stream>>>(guide, feat16, P, out);
}

// Round 3
// 166.900 us; speedup vs baseline: 4.7876x; 1.1334x over previous
//
#include <hip/hip_runtime.h>
#include <math.h>

#define NEG_BIG (-1e30f)

typedef _Float16 half8 __attribute__((ext_vector_type(8)));
typedef _Float16 half2v __attribute__((ext_vector_type(2)));
typedef float floatx4 __attribute__((ext_vector_type(4)));

// ---------------------------------------------------------------------------
// Kernel 0 (fused aux): blocks 0..383 convert feat fp32->fp16 (A-operand
// layout [c][p]); block 384 computes per-LR-pixel params:
//   PQ[p] = {A2, B2, C2, iC}  quadratic form:  a^2*iA + b^2*iB
//           = A2*dx^2 + B2*dx*dy + C2*dy^2   (rotation pre-expanded)
//   PG[p] = {glr0, glr1, glr2, max(sx,sy)}
// ---------------------------------------------------------------------------
__global__ __launch_bounds__(256) void setup_all(
    const float* __restrict__ feat, const float* __restrict__ guide,
    const float* __restrict__ sx_raw, const float* __restrict__ sy_raw,
    const float* __restrict__ th_raw, const float* __restrict__ sr_raw,
    _Float16* __restrict__ feat16, float4* __restrict__ PQ,
    float4* __restrict__ PG)
{
    const int b = blockIdx.x, t = threadIdx.x;
    if (b < 384) {
        int i = b*256 + t;
        feat16[i] = (_Float16)feat[i];
        return;
    }
    float sx = expf(sx_raw[t]);
    float sy = expf(sy_raw[t]);
    float th = 3.14159265358979323846f * tanhf(th_raw[t]);
    float sr = expf(sr_raw[t]);
    float sxg = fmaxf(sx, 1e-6f), syg = fmaxf(sy, 1e-6f), srg = fmaxf(sr, 1e-6f);
    float iA = 1.f / (2.f*sxg*sxg + 1e-8f);
    float iB = 1.f / (2.f*syg*syg + 1e-8f);
    float iC = 1.f / (2.f*srg*srg + 1e-8f);
    float ct = cosf(th), st = sinf(th);
    float A2 = iA*ct*ct + iB*st*st;
    float B2 = 2.f*ct*st*(iA - iB);
    float C2 = iA*st*st + iB*ct*ct;
    PQ[t] = make_float4(A2, B2, C2, iC);
    int i = t >> 4, j = t & 15;
    int y0 = 16*i + 7, x0 = 16*j + 7;   // bilinear 256->16 == 2x2 average
    float g[3];
#pragma unroll
    for (int c = 0; c < 3; ++c) {
        const float* gp = guide + c*65536;
        g[c] = 0.25f*(gp[y0*256 + x0]     + gp[y0*256 + x0 + 1] +
                      gp[(y0+1)*256 + x0] + gp[(y0+1)*256 + x0 + 1]);
    }
    PG[t] = make_float4(g[0], g[1], g[2], fmaxf(sx, sy));
}

// ---------------------------------------------------------------------------
// Kernel 1: main fused JBU.
// Block = 1x32 HR pixel strip. 256 threads = 32 pixels (q) x 8 p-groups (grp),
// re-viewed as 4 waves x 96 channels for the MFMA phase.
//
// Table: LC[p][(R-1)*2+vcb] = ln(multiplicity) for ALL R in [1,8] and the
//   block's two vc values -- built cooperatively once (cnt depends only on
//   (uc, vc, R, p)); phase 1 is then a pure lookup + quadratic form.
// Phase 1: lw[pi] = LC[...] - (A2 dx^2 + B2 dx dy + C2 dy^2 + iC gd), regs.
// Phase 2: s = exp(lw - m) -> fp16, paired b32 stores into XOR-swizzled Wb;
//          den = sum of fp16-rounded s.
// Phase 3: out[c,pix] = invden * (feat16[384,256] @ Wb[256,32]) via
//          mfma_f32_16x16x32_f16; A from global (L2-hot), B from LDS.
// LDS: 4+4+16+16+~1.2 = ~41.3 KB -> 3 blocks/CU.
// ---------------------------------------------------------------------------
__global__ __launch_bounds__(256, 3) void jbu_main(
    const float* __restrict__ guide, const _Float16* __restrict__ feat16,
    const float4* __restrict__ PQ, const float4* __restrict__ PG,
    float* __restrict__ out)
{
    __shared__ float4 sPQ[256];                     // 4 KB
    __shared__ float4 sPG[256];                     // 4 KB
    __shared__ float  LC[4096];                     // 16 KB  [p][ (R-1)*2+vcb ]
    __shared__ __align__(16) _Float16 Wb[32][256];  // 16 KB, row=pixel, swizzled
    __shared__ float red[8][32];
    __shared__ float invden[32];

    const int t = threadIdx.x;
    sPQ[t] = PQ[t];
    sPG[t] = PG[t];

    const int q   = t & 31;
    const int grp = t >> 5;
    const int Y   = blockIdx.y;
    const int X0  = blockIdx.x << 5;
    const int X   = X0 + q;
    const float Yf = (float)Y, Xf = (float)X;
    const int uc  = Y >> 4;           // == clip(round(u),0,15) exactly
    const int vc0 = X0 >> 4;

    // ---- Build LC: thread t -> Pu = t>>4, col = t&15 (R=(col>>1)+1, vcb=col&1)
    {
        const int Pu  = t >> 4;
        const int col = t & 15;
        const int Rt  = (col >> 1) + 1;
        const int vcb = col & 1;
        const int vc  = vc0 + vcb;
        const int R2  = Rt * Rt;
        int ylo = (Pu == 0)  ? -8 : (Pu - uc);
        int yhi = (Pu == 15) ?  8 : (Pu - uc);
        ylo = max(ylo, -8); yhi = min(yhi, 8);
        int cnt[16];
#pragma unroll
        for (int Pv = 0; Pv < 16; ++Pv) cnt[Pv] = 0;
        for (int dY = ylo; dY <= yhi; ++dY) {
            int lim = R2 - dY*dY;
            if (lim >= 0) {
                int r = (int)sqrtf((float)lim);   // exact for ints <= 64
#pragma unroll
                for (int Pv = 0; Pv < 16; ++Pv) {
                    int xlo = (Pv == 0)  ? -8 : (Pv - vc);
                    int xhi = (Pv == 15) ?  8 : (Pv - vc);
                    xlo = max(xlo, -8); xhi = min(xhi, 8);
                    int lo = max(xlo, -r), hi = min(xhi, r);
                    cnt[Pv] += max(0, hi - lo + 1);
                }
            }
        }
#pragma unroll
        for (int Pv = 0; Pv < 16; ++Pv)
            LC[(Pu*16 + Pv)*16 + col] =
                (cnt[Pv] > 0) ? __logf((float)cnt[Pv]) : NEG_BIG;
    }
    __syncthreads();   // publishes sPQ, sPG, LC

    // ---- Per-pixel R from bilinear upsample of max(sx,sy) ----
    float u = (Yf + 0.5f)*0.0625f - 0.5f;
    float v = (Xf + 0.5f)*0.0625f - 0.5f;
    float ysc = fmaxf(u, 0.f), xsc = fmaxf(v, 0.f);
    int y0 = (int)ysc, x0 = (int)xsc;
    int y1 = min(y0 + 1, 15), x1 = min(x0 + 1, 15);
    float wy = ysc - (float)y0, wx = xsc - (float)x0;
    float s00 = sPG[y0*16 + x0].w, s01 = sPG[y0*16 + x1].w;
    float s10 = sPG[y1*16 + x0].w, s11 = sPG[y1*16 + x1].w;
    float sig = (1.f - wy)*((1.f - wx)*s00 + wx*s01)
              +        wy *((1.f - wx)*s10 + wx*s11);
    float Rf = fminf(fmaxf(ceilf(2.f*sig), 1.f), 8.f);
    const int colq = ((int)Rf - 1)*2 + (q >> 4);   // vcb = q>>4

    const float g0 = guide[          (Y << 8) + X];
    const float g1 = guide[ 65536 + ((Y << 8) + X)];
    const float g2 = guide[131072 + ((Y << 8) + X)];

    // ---- Phase 1: lw = ln(cnt) - quadform, kept in registers ----
    const int pbase = grp << 5;
    const float dy0 = Yf - (16.f*(float)(grp*2) + 7.5f);
    float lw[32];
    float mloc = NEG_BIG;
#pragma unroll
    for (int pi = 0; pi < 32; ++pi) {
        int p = pbase + pi;
        float4 Q = sPQ[p];
        float4 G = sPG[p];
        float dy = (pi < 16) ? dy0 : (dy0 - 16.f);
        float dx = Xf - (16.f*(float)(pi & 15) + 7.5f);
        float d0 = g0 - G.x, d1 = g1 - G.y, d2 = g2 - G.z;
        float gd = d0*d0 + d1*d1 + d2*d2;
        float quad = Q.x*(dx*dx) + Q.y*(dx*dy) + Q.z*(dy*dy) + Q.w*gd;
        float w = LC[p*16 + colq] - quad;
        lw[pi] = w;
        mloc = fmaxf(mloc, w);
    }
    red[grp][q] = mloc;
    __syncthreads();
    float m = red[0][q];
#pragma unroll
    for (int g = 1; g < 8; ++g) m = fmaxf(m, red[g][q]);
    __syncthreads();   // before red is reused for den

    // ---- Phase 2: exp, fp16 round, paired swizzled LDS stores, denominator --
    float dloc = 0.f;
#pragma unroll
    for (int pi = 0; pi < 32; pi += 2) {
        int p = pbase + pi;
        float s0 = __expf(lw[pi]     - m);   // NEG_BIG entries underflow to 0
        float s1 = __expf(lw[pi + 1] - m);
        half2v hh; hh[0] = (_Float16)s0; hh[1] = (_Float16)s1;
        int chunk = ((p >> 3) ^ q) & 31;     // 16B-chunk XOR swizzle
        *(half2v*)&Wb[q][chunk*8 + (p & 7)] = hh;
        dloc += (float)hh[0] + (float)hh[1]; // den consistent with fp16 weights
    }
    red[grp][q] = dloc;
    __syncthreads();                         // publishes Wb + den partials
    float den = 0.f;
#pragma unroll
    for (int g = 0; g < 8; ++g) den += red[g][q];
    if (grp == 0) invden[q] = 1.f / fmaxf(den, 1e-8f);
    __syncthreads();

    // ---- Phase 3: MFMA GEMM: out[c,pix] = invden * feat16 @ Wb ----
    const int lane = t & 63;
    const int wv   = t >> 6;          // wave 0..3 -> channels wv*96..+96
    const int mrow = lane & 15;
    const int quad = lane >> 4;
    const int c0   = wv * 96;

    floatx4 acc[6][2] = {};
    const _Float16* fbase = feat16 + (c0 + mrow)*256 + quad*8;

#pragma unroll
    for (int ks = 0; ks < 8; ++ks) {
        half8 a[6];
#pragma unroll
        for (int mt = 0; mt < 6; ++mt)
            a[mt] = *(const half8*)(fbase + mt*16*256 + ks*32);
        half8 b[2];
#pragma unroll
        for (int nt = 0; nt < 2; ++nt) {
            int pix = nt*16 + mrow;
            int chunk = ((ks*4 + quad) ^ pix) & 31;
            b[nt] = *(const half8*)(&Wb[pix][chunk*8]);
        }
#pragma unroll
        for (int mt = 0; mt < 6; ++mt)
#pragma unroll
            for (int nt = 0; nt < 2; ++nt)
                acc[mt][nt] = __builtin_amdgcn_mfma_f32_16x16x32_f16(
                    a[mt], b[nt], acc[mt][nt], 0, 0, 0);
    }

    // ---- Epilogue: scale by invden, store ----
    const int outbase = (Y << 8) + X0;
#pragma unroll
    for (int nt = 0; nt < 2; ++nt) {
        float idv = invden[nt*16 + mrow];
#pragma unroll
        for (int mt = 0; mt < 6; ++mt) {
            int crow = c0 + mt*16 + quad*4;
            float* o = out + (size_t)crow*65536 + outbase + nt*16 + mrow;
#pragma unroll
            for (int r = 0; r < 4; ++r)
                o[(size_t)r*65536] = acc[mt][nt][r] * idv;
        }
    }
}

// ---------------------------------------------------------------------------
extern "C" void kernel_launch(void* const* d_in, const int* in_sizes, int n_in,
                              void* d_out, int out_size, void* d_ws, size_t ws_size,
                              hipStream_t stream)
{
    const float* feat   = (const float*)d_in[0];   // [1,384,16,16]
    const float* guide  = (const float*)d_in[1];   // [1,3,256,256]
    const float* sx_raw = (const float*)d_in[2];   // [1,1,16,16]
    const float* sy_raw = (const float*)d_in[3];
    const float* th_raw = (const float*)d_in[4];
    const float* sr_raw = (const float*)d_in[5];
    float* out = (float*)d_out;                    // [1,384,256,256]

    _Float16* feat16 = (_Float16*)d_ws;                         // 192 KB
    float4*   PQ     = (float4*)((char*)d_ws + 196608);         // 4 KB
    float4*   PG     = (float4*)((char*)d_ws + 196608 + 4096);  // 4 KB

    setup_all<<<385, 256, 0, stream>>>(feat, guide, sx_raw, sy_raw, th_raw,
                                       sr_raw, feat16, PQ, PG);
    jbu_main<<<dim3(8, 256), 256, 0, stream>>>(guide, feat16, PQ, PG, out);
}

// Round 4
// 161.954 us; speedup vs baseline: 4.9339x; 1.0305x over previous
//
#include <hip/hip_runtime.h>
#include <math.h>

#define NEG_BIG  (-1e30f)
#define NEG_H16  (-60000.0f)   // "empty" marker safe in fp16

typedef _Float16 half8  __attribute__((ext_vector_type(8)));
typedef _Float16 half2v __attribute__((ext_vector_type(2)));
typedef float    floatx4 __attribute__((ext_vector_type(4)));

// ---------------------------------------------------------------------------
// Kernel 0 (fused aux): blocks 0..383 convert feat fp32->fp16 (A-operand
// layout [c][p]); block 384 computes per-LR-pixel params:
//   PQ[p] = {A2, B2, C2, iC} quadratic form (rotation pre-expanded)
//   PG[p] = {glr0, glr1, glr2, max(sx,sy)}
// ---------------------------------------------------------------------------
__global__ __launch_bounds__(256) void setup_all(
    const float* __restrict__ feat, const float* __restrict__ guide,
    const float* __restrict__ sx_raw, const float* __restrict__ sy_raw,
    const float* __restrict__ th_raw, const float* __restrict__ sr_raw,
    _Float16* __restrict__ feat16, float4* __restrict__ PQ,
    float4* __restrict__ PG)
{
    const int b = blockIdx.x, t = threadIdx.x;
    if (b < 384) {
        int i = b*256 + t;
        feat16[i] = (_Float16)feat[i];
        return;
    }
    float sx = expf(sx_raw[t]);
    float sy = expf(sy_raw[t]);
    float th = 3.14159265358979323846f * tanhf(th_raw[t]);
    float sr = expf(sr_raw[t]);
    float sxg = fmaxf(sx, 1e-6f), syg = fmaxf(sy, 1e-6f), srg = fmaxf(sr, 1e-6f);
    float iA = 1.f / (2.f*sxg*sxg + 1e-8f);
    float iB = 1.f / (2.f*syg*syg + 1e-8f);
    float iC = 1.f / (2.f*srg*srg + 1e-8f);
    float ct = cosf(th), st = sinf(th);
    float A2 = iA*ct*ct + iB*st*st;
    float B2 = 2.f*ct*st*(iA - iB);
    float C2 = iA*st*st + iB*ct*ct;
    PQ[t] = make_float4(A2, B2, C2, iC);
    int i = t >> 4, j = t & 15;
    int y0 = 16*i + 7, x0 = 16*j + 7;   // bilinear 256->16 == 2x2 average
    float g[3];
#pragma unroll
    for (int c = 0; c < 3; ++c) {
        const float* gp = guide + c*65536;
        g[c] = 0.25f*(gp[y0*256 + x0]     + gp[y0*256 + x0 + 1] +
                      gp[(y0+1)*256 + x0] + gp[(y0+1)*256 + x0 + 1]);
    }
    PG[t] = make_float4(g[0], g[1], g[2], fmaxf(sx, sy));
}

// ---------------------------------------------------------------------------
// Kernel 1: main fused JBU.
// Block = 1x32 HR pixel strip. 256 threads = 32 pixels (q) x 8 p-groups (grp),
// re-viewed as 4 waves x 96 channels for the MFMA phase.
//
// LC table (fp16): LC[p][(R-1)*2+vcb] = ln(multiplicity) for R in [1,8] and
//   the block's two vc values. Interior columns use the closed-form count
//   |[-s,s] ∩ [ylo,yhi]|, s=floor(sqrt(R^2-d^2)); only border columns loop.
// Phase 1: lw = ln(cnt) - quadform (regs); per-pixel max via shfl_xor(32)
//   + one LDS round-trip.
// Phase 2: s = exp(lw-m) -> fp16 into XOR-swizzled Wb; den partials likewise.
// Phase 3: out[c,pix] = invden * (feat16[384,256] @ Wb[256,32]) via
//   mfma_f32_16x16x32_f16; A from global (L2-hot), B from LDS; invden
//   recomputed per-thread from den partials (no extra barrier).
// LDS = 4+4+8+16+0.5+0.5 = 33.8 KB -> 4 blocks/CU @ <=128 VGPR.
// ---------------------------------------------------------------------------
__global__ __launch_bounds__(256, 4) void jbu_main(
    const float* __restrict__ guide, const _Float16* __restrict__ feat16,
    const float4* __restrict__ PQ, const float4* __restrict__ PG,
    float* __restrict__ out)
{
    __shared__ float4 sPQ[256];                     // 4 KB
    __shared__ float4 sPG[256];                     // 4 KB
    __shared__ _Float16 LCh[4096];                  // 8 KB  [p][(R-1)*2+vcb]
    __shared__ __align__(16) _Float16 Wb[32][256];  // 16 KB, row=pixel, swizzled
    __shared__ float redM[4][32];                   // per-wave max partials
    __shared__ float redD[4][32];                   // per-wave den partials

    const int t = threadIdx.x;
    sPQ[t] = PQ[t];
    sPG[t] = PG[t];

    const int q    = t & 31;
    const int grp  = t >> 5;
    const int wv   = t >> 6;
    const int Y    = blockIdx.y;
    const int X0   = blockIdx.x << 5;
    const int X    = X0 + q;
    const float Yf = (float)Y, Xf = (float)X;
    const int uc   = Y >> 4;          // == clip(round(u),0,15) exactly
    const int vc0  = X0 >> 4;

    // ---- Build LC: thread t -> Pu = t>>4, col = t&15 (R=(col>>1)+1, vcb) ----
    {
        const int Pu  = t >> 4;
        const int col = t & 15;
        const int Rt  = (col >> 1) + 1;
        const int vc  = vc0 + (col & 1);
        const int R2  = Rt * Rt;
        int ylo = (Pu == 0)  ? -8 : (Pu - uc);
        int yhi = (Pu == 15) ?  8 : (Pu - uc);
        ylo = max(ylo, -8); yhi = min(yhi, 8);
        int cnt[16];
        // interior columns: closed form
#pragma unroll
        for (int Pv = 1; Pv < 15; ++Pv) {
            int d = Pv - vc;
            int lim = R2 - d*d;
            int c = 0;
            if (lim >= 0 && ylo <= yhi) {
                int s = (int)sqrtf((float)lim);   // exact for ints <= 64
                c = max(0, min(yhi, s) - max(ylo, -s) + 1);
            }
            cnt[Pv] = c;
        }
        // border columns: loop (early-out when interval empty)
        cnt[0] = 0;
        if (-vc >= -8) {
            for (int dY = ylo; dY <= yhi; ++dY) {
                int lim = R2 - dY*dY;
                if (lim >= 0) {
                    int r = (int)sqrtf((float)lim);
                    cnt[0] += max(0, min(-vc, r) + r + 1);   // lo = -r
                }
            }
        }
        cnt[15] = 0;
        if (15 - vc <= 8) {
            for (int dY = ylo; dY <= yhi; ++dY) {
                int lim = R2 - dY*dY;
                if (lim >= 0) {
                    int r = (int)sqrtf((float)lim);
                    cnt[15] += max(0, r - max(15 - vc, -r) + 1);
                }
            }
        }
#pragma unroll
        for (int Pv = 0; Pv < 16; ++Pv)
            LCh[(Pu*16 + Pv)*16 + col] = (_Float16)
                ((cnt[Pv] > 0) ? __logf((float)cnt[Pv]) : NEG_H16);
    }
    __syncthreads();   // B1: publishes sPQ, sPG, LCh

    // ---- Per-pixel R from bilinear upsample of max(sx,sy) ----
    float u = (Yf + 0.5f)*0.0625f - 0.5f;
    float v = (Xf + 0.5f)*0.0625f - 0.5f;
    float ysc = fmaxf(u, 0.f), xsc = fmaxf(v, 0.f);
    int y0 = (int)ysc, x0 = (int)xsc;
    int y1 = min(y0 + 1, 15), x1 = min(x0 + 1, 15);
    float wy = ysc - (float)y0, wx = xsc - (float)x0;
    float s00 = sPG[y0*16 + x0].w, s01 = sPG[y0*16 + x1].w;
    float s10 = sPG[y1*16 + x0].w, s11 = sPG[y1*16 + x1].w;
    float sig = (1.f - wy)*((1.f - wx)*s00 + wx*s01)
              +        wy *((1.f - wx)*s10 + wx*s11);
    float Rf = fminf(fmaxf(ceilf(2.f*sig), 1.f), 8.f);
    const int colq = ((int)Rf - 1)*2 + (q >> 4);   // vcb = q>>4

    const float g0 = guide[          (Y << 8) + X];
    const float g1 = guide[ 65536 + ((Y << 8) + X)];
    const float g2 = guide[131072 + ((Y << 8) + X)];

    // ---- Phase 1: lw = ln(cnt) - quadform, kept in registers ----
    const int pbase = grp << 5;
    const float dy0 = Yf - (16.f*(float)(grp*2) + 7.5f);
    float lw[32];
    float mloc = NEG_BIG;
#pragma unroll
    for (int pi = 0; pi < 32; ++pi) {
        int p = pbase + pi;
        float4 Q = sPQ[p];
        float4 G = sPG[p];
        float dy = (pi < 16) ? dy0 : (dy0 - 16.f);
        float dx = Xf - (16.f*(float)(pi & 15) + 7.5f);
        float d0 = g0 - G.x, d1 = g1 - G.y, d2 = g2 - G.z;
        float gd = d0*d0 + d1*d1 + d2*d2;
        float quad = Q.x*(dx*dx) + Q.y*(dx*dy) + Q.z*(dy*dy) + Q.w*gd;
        float w = (float)LCh[p*16 + colq] - quad;
        lw[pi] = w;
        mloc = fmaxf(mloc, w);
    }
    mloc = fmaxf(mloc, __shfl_xor(mloc, 32, 64));  // combine wave's 2 p-groups
    redM[wv][q] = mloc;
    __syncthreads();   // B2
    float m = fmaxf(fmaxf(redM[0][q], redM[1][q]),
                    fmaxf(redM[2][q], redM[3][q]));

    // ---- Phase 2: exp, fp16 round, paired swizzled LDS stores, den ----
    float dloc = 0.f;
#pragma unroll
    for (int pi = 0; pi < 32; pi += 2) {
        int p = pbase + pi;
        float e0 = __expf(lw[pi]     - m);   // empty entries underflow to 0
        float e1 = __expf(lw[pi + 1] - m);
        half2v hh; hh[0] = (_Float16)e0; hh[1] = (_Float16)e1;
        int chunk = ((p >> 3) ^ q) & 31;     // 16B-chunk XOR swizzle
        *(half2v*)&Wb[q][chunk*8 + (p & 7)] = hh;
        dloc += (float)hh[0] + (float)hh[1]; // den consistent with fp16 weights
    }
    dloc += __shfl_xor(dloc, 32, 64);
    redD[wv][q] = dloc;
    __syncthreads();   // B3: publishes Wb + redD

    // ---- Phase 3: MFMA GEMM: out[c,pix] = invden * feat16 @ Wb ----
    const int lane = t & 63;
    const int mrow = lane & 15;
    const int quad = lane >> 4;
    const int c0   = wv * 96;

    float idv[2];
#pragma unroll
    for (int nt = 0; nt < 2; ++nt) {
        int pix = nt*16 + mrow;
        float den = redD[0][pix] + redD[1][pix] + redD[2][pix] + redD[3][pix];
        idv[nt] = 1.f / fmaxf(den, 1e-8f);
    }

    floatx4 acc[6][2] = {};
    const _Float16* fbase = feat16 + (c0 + mrow)*256 + quad*8;

#pragma unroll
    for (int ks = 0; ks < 8; ++ks) {
        half8 a[6];
#pragma unroll
        for (int mt = 0; mt < 6; ++mt)
            a[mt] = *(const half8*)(fbase + mt*16*256 + ks*32);
        half8 b[2];
#pragma unroll
        for (int nt = 0; nt < 2; ++nt) {
            int pix = nt*16 + mrow;
            int chunk = ((ks*4 + quad) ^ pix) & 31;
            b[nt] = *(const half8*)(&Wb[pix][chunk*8]);
        }
#pragma unroll
        for (int mt = 0; mt < 6; ++mt)
#pragma unroll
            for (int nt = 0; nt < 2; ++nt)
                acc[mt][nt] = __builtin_amdgcn_mfma_f32_16x16x32_f16(
                    a[mt], b[nt], acc[mt][nt], 0, 0, 0);
    }

    // ---- Epilogue: scale by invden, store ----
    const int outbase = (Y << 8) + X0;
#pragma unroll
    for (int nt = 0; nt < 2; ++nt) {
#pragma unroll
        for (int mt = 0; mt < 6; ++mt) {
            int crow = c0 + mt*16 + quad*4;
            float* o = out + (size_t)crow*65536 + outbase + nt*16 + mrow;
#pragma unroll
            for (int r = 0; r < 4; ++r)
                o[(size_t)r*65536] = acc[mt][nt][r] * idv[nt];
        }
    }
}

// ---------------------------------------------------------------------------
extern "C" void kernel_launch(void* const* d_in, const int* in_sizes, int n_in,
                              void* d_out, int out_size, void* d_ws, size_t ws_size,
                              hipStream_t stream)
{
    const float* feat   = (const float*)d_in[0];   // [1,384,16,16]
    const float* guide  = (const float*)d_in[1];   // [1,3,256,256]
    const float* sx_raw = (const float*)d_in[2];   // [1,1,16,16]
    const float* sy_raw = (const float*)d_in[3];
    const float* th_raw = (const float*)d_in[4];
    const float* sr_raw = (const float*)d_in[5];
    float* out = (float*)d_out;                    // [1,384,256,256]

    _Float16* feat16 = (_Float16*)d_ws;                         // 192 KB
    float4*   PQ     = (float4*)((char*)d_ws + 196608);         // 4 KB
    float4*   PG     = (float4*)((char*)d_ws + 196608 + 4096);  // 4 KB

    setup_all<<<385, 256, 0, stream>>>(feat, guide, sx_raw, sy_raw, th_raw,
                                       sr_raw, feat16, PQ, PG);
    jbu_main<<<dim3(8, 256), 256, 0, stream>>>(guide, feat16, PQ, PG, out);
}